// Round 6
// baseline (276.512 us; speedup 1.0000x reference)
//
#include <hip/hip_runtime.h>
#include <hip/hip_bf16.h>

#define F 64
#define R 64
#define O 64
#define BLOCK_B 64   // batch rows per block (512 threads, 8 waves)

typedef short bf16x8 __attribute__((ext_vector_type(8)));
typedef float f32x4 __attribute__((ext_vector_type(4)));
typedef float f32x2 __attribute__((ext_vector_type(2)));

static __device__ __forceinline__ short f2bf(float f) {
    unsigned u = __builtin_bit_cast(unsigned, f);
    unsigned r = (u + 0x7fffu + ((u >> 16) & 1u)) >> 16;
    return (short)r;
}

// ---------------------------------------------------------------------------
// Prep kernel (flat, 146 blocks x 256) — round-3 variant (lowest overhead).
//   threads [0, 33280): pack W (fp32) -> Wpk (bf16, MFMA B-fragment order):
//     dst bf16x8 idx = ((nt*65 + f)*2 + kk)*64 + lane
//     elem j = W[o][f*64 + r], o = nt*16+(lane&15), r = (lane>>4)*8 + j + kk*32
//   threads [33280, 37376): prm[u] = {s, mn*s, t, c}, u = f*64 + r
// ---------------------------------------------------------------------------
__global__ __launch_bounds__(256) void fq_prep(
        const float* __restrict__ tt, const float* __restrict__ mean,
        const float* __restrict__ std_, const float* __restrict__ W,
        float* __restrict__ prm, unsigned short* __restrict__ Wpk)
{
    const int tg = blockIdx.x * 256 + threadIdx.x;
    if (tg < 65 * 512) {
        const int f    = tg >> 9;
        const int u8   = tg & 511;
        const int lane = u8 & 63;
        const int kk   = (u8 >> 6) & 1;
        const int nt   = u8 >> 7;
        const int o    = nt * 16 + (lane & 15);
        const int rb   = ((lane >> 4) << 3) + kk * 32;
        const float* src = W + o * 4160 + f * 64 + rb;
        unsigned short v[8];
#pragma unroll
        for (int j = 0; j < 8; ++j) v[j] = (unsigned short)f2bf(src[j]);
        const int dst = ((nt * 65 + f) * 2 + kk) * 64 + lane;
        *(bf16x8*)(Wpk + (size_t)dst * 8) = *(bf16x8*)v;
    } else if (tg < 65 * 512 + 4096) {
        const int u = tg - 65 * 512;
        float sd = std_[u];
        float mn = mean[u];
        float th = tanhf(tt[u]);
        float s  = 1.2011224087864498f / sd;  // sqrt(log2(e)) / std
        float4 p;
        p.x = s;
        p.y = mn * s;
        p.z = th;
        p.w = 0.5f * (1.0f - th);
        ((float4*)prm)[u] = p;
    }
}

// ---------------------------------------------------------------------------
// Main fused kernel: block = 64 batch rows, 512 threads (8 waves).
// wave w: nt = w>>1 (16 output cols), fh = w&1 (K-half).
// Stage 0: transpose X slab into LDS xt[f][row].
// Stage 1: wave w computes fire for rows 8w..8w+7 (lane = rule r).
// Stage 2: each wave streams ONLY its K-half of the nt W-slab (65 KB) and
//          computes all 4 row-tiles (64-row reuse, round-5 traffic) with
//          software-prefetched W loads. fh partials merge through LDS.
// ---------------------------------------------------------------------------
__global__ __launch_bounds__(512, 4) void fq_main(
        const float* __restrict__ X,
        const float4* __restrict__ prm,
        const bf16x8* __restrict__ Wp,
        float* __restrict__ out)
{
    __shared__ __align__(16) float xt[64][68];        // [f][row]
    __shared__ __align__(16) float fire_lds[64][68];  // [row][r]
    __shared__ float rinv[BLOCK_B];
    __shared__ __align__(16) float epi[4][4][64][4];  // [nt][m][lane][reg]

    const int t    = threadIdx.x;
    const int lane = t & 63;
    const int w    = __builtin_amdgcn_readfirstlane(t >> 6);  // wave 0..7
    const int b0   = blockIdx.x * BLOCK_B;

    // ---- stage 0: transpose X slab into xt (coalesced reads) ---------------
    {
        const int f4 = (t & 15) * 4;
        const int r0 = t >> 4;           // 0..31
#pragma unroll
        for (int it = 0; it < 2; ++it) {
            const int row = r0 + 32 * it;
            float4 xv = *(const float4*)(X + (size_t)(b0 + row) * 64 + f4);
            xt[f4 + 0][row] = xv.x;
            xt[f4 + 1][row] = xv.y;
            xt[f4 + 2][row] = xv.z;
            xt[f4 + 3][row] = xv.w;
        }
    }
    __syncthreads();

    // ---- stage 1: firing strengths, rows 8w..8w+7, lane = r ----------------
    {
        f32x2 fire2[4];
#pragma unroll
        for (int i = 0; i < 4; ++i) fire2[i] = (f32x2){1.f, 1.f};
        const int r0 = 8 * w;
        float4 p = prm[lane];            // f = 0
#pragma unroll 2
        for (int f = 0; f < F; ++f) {
            float4 pn = prm[(f + 1) * 64 + lane];  // prefetch (f=63 reads into
                                                   // Wpk region — valid, unused)
            f32x4 xa = *(const f32x4*)&xt[f][r0];      // rows r0..r0+3 (bcast)
            f32x4 xb = *(const f32x4*)&xt[f][r0 + 4];  // rows r0+4..r0+7
            f32x2 t2 = (f32x2){p.z, p.z};
            f32x2 c2 = (f32x2){p.w, p.w};
            f32x2 z0, z1, z2, z3;
            z0.x = __builtin_fmaf(xa[0], p.x, -p.y);
            z0.y = __builtin_fmaf(xa[1], p.x, -p.y);
            z1.x = __builtin_fmaf(xa[2], p.x, -p.y);
            z1.y = __builtin_fmaf(xa[3], p.x, -p.y);
            z2.x = __builtin_fmaf(xb[0], p.x, -p.y);
            z2.y = __builtin_fmaf(xb[1], p.x, -p.y);
            z3.x = __builtin_fmaf(xb[2], p.x, -p.y);
            z3.y = __builtin_fmaf(xb[3], p.x, -p.y);
            f32x2 n0 = -(z0 * z0), n1 = -(z1 * z1);
            f32x2 n2 = -(z2 * z2), n3 = -(z3 * z3);
            f32x2 g0, g1, g2, g3;
            g0.x = __builtin_amdgcn_exp2f(n0.x); g0.y = __builtin_amdgcn_exp2f(n0.y);
            g1.x = __builtin_amdgcn_exp2f(n1.x); g1.y = __builtin_amdgcn_exp2f(n1.y);
            g2.x = __builtin_amdgcn_exp2f(n2.x); g2.y = __builtin_amdgcn_exp2f(n2.y);
            g3.x = __builtin_amdgcn_exp2f(n3.x); g3.y = __builtin_amdgcn_exp2f(n3.y);
            fire2[0] *= g0 * t2 + c2;
            fire2[1] *= g1 * t2 + c2;
            fire2[2] *= g2 * t2 + c2;
            fire2[3] *= g3 * t2 + c2;
            p = pn;
        }
#pragma unroll
        for (int i = 0; i < 4; ++i) {
            fire_lds[r0 + 2 * i][lane]     = fire2[i].x;
            fire_lds[r0 + 2 * i + 1][lane] = fire2[i].y;
        }
    }
    __syncthreads();

    // ---- row sums: 8 threads per row, shuffle-reduce -----------------------
    {
        const int row = t >> 3;
        const int c8  = (t & 7) * 8;
        f32x4 s0 = *(const f32x4*)&fire_lds[row][c8];
        f32x4 s1 = *(const f32x4*)&fire_lds[row][c8 + 4];
        float s = (s0[0] + s0[1]) + (s0[2] + s0[3]) +
                  (s1[0] + s1[1]) + (s1[2] + s1[3]);
        s += __shfl_xor(s, 1);
        s += __shfl_xor(s, 2);
        s += __shfl_xor(s, 4);
        if ((t & 7) == 0) rinv[row] = 1.0f / s;
    }
    __syncthreads();

    // ---- stage 2: K-split GEMM, 4 row-tiles per wave -----------------------
    const int m_in = lane & 15;
    const int quad = lane >> 4;
    const int nt   = w >> 1;
    const int fh   = w & 1;
    const int q8   = quad * 8;

    bf16x8 wfrag[4][2];   // [mrow][kk]
#pragma unroll
    for (int m = 0; m < 4; ++m) {
        const int myrow = 16 * m + m_in;
        const float rs  = rinv[myrow];
#pragma unroll
        for (int kk = 0; kk < 2; ++kk) {
            f32x4 a = *(const f32x4*)&fire_lds[myrow][q8 + kk * 32];
            f32x4 b = *(const f32x4*)&fire_lds[myrow][q8 + kk * 32 + 4];
            wfrag[m][kk][0] = f2bf(a[0] * rs); wfrag[m][kk][1] = f2bf(a[1] * rs);
            wfrag[m][kk][2] = f2bf(a[2] * rs); wfrag[m][kk][3] = f2bf(a[3] * rs);
            wfrag[m][kk][4] = f2bf(b[0] * rs); wfrag[m][kk][5] = f2bf(b[1] * rs);
            wfrag[m][kk][6] = f2bf(b[2] * rs); wfrag[m][kk][7] = f2bf(b[3] * rs);
        }
    }

    // slab s of this nt: bf16x8 offsets (2s)*64 and (2s+1)*64 from wpb
    const bf16x8* wpb = Wp + (size_t)(nt * 130) * 64 + lane;
    const int s0 = fh * 32;             // first slab of this K-half
    const int ns = 32;                  // slabs in the main loop (both halves)

    f32x4 acc[4];
#pragma unroll
    for (int m = 0; m < 4; ++m) acc[m] = (f32x4){0.f, 0.f, 0.f, 0.f};
    const f32x4 z4 = (f32x4){0.f, 0.f, 0.f, 0.f};

    // software pipeline: W-pair for slab s0 preloaded; prefetch s+1 (clamped
    // to 64 = bias slab, always valid; for fh=1 the exit prefetch IS the bias)
    bf16x8 nb0 = wpb[(2 * s0) * 64];
    bf16x8 nb1 = wpb[(2 * s0 + 1) * 64];
    for (int i = 0; i < ns; ++i) {
        const int f  = s0 + i;
        bf16x8 bb0 = nb0, bb1 = nb1;
        const int sp = (f + 1 < 64) ? f + 1 : 64;
        nb0 = wpb[(2 * sp) * 64];
        nb1 = wpb[(2 * sp + 1) * 64];
#pragma unroll
        for (int m = 0; m < 4; ++m) {
            f32x4 U = __builtin_amdgcn_mfma_f32_16x16x32_bf16(wfrag[m][0], bb0, z4, 0, 0, 0);
            U = __builtin_amdgcn_mfma_f32_16x16x32_bf16(wfrag[m][1], bb1, U, 0, 0, 0);
            f32x4 xv = *(const f32x4*)&xt[f][16 * m + quad * 4];  // bcast b128
#pragma unroll
            for (int reg = 0; reg < 4; ++reg)
                acc[m][reg] = __builtin_fmaf(xv[reg], U[reg], acc[m][reg]);
        }
    }

    if (fh == 1) {
        // bias slab (x = 1): regs already prefetched in nb0/nb1
#pragma unroll
        for (int m = 0; m < 4; ++m) {
            f32x4 U = __builtin_amdgcn_mfma_f32_16x16x32_bf16(wfrag[m][0], nb0, z4, 0, 0, 0);
            U = __builtin_amdgcn_mfma_f32_16x16x32_bf16(wfrag[m][1], nb1, U, 0, 0, 0);
#pragma unroll
            for (int reg = 0; reg < 4; ++reg)
                acc[m][reg] += U[reg];
        }
#pragma unroll
        for (int m = 0; m < 4; ++m)
            *(f32x4*)&epi[nt][m][lane][0] = acc[m];
    }
    __syncthreads();

    if (fh == 0) {
#pragma unroll
        for (int m = 0; m < 4; ++m) {
            f32x4 r = acc[m] + *(const f32x4*)&epi[nt][m][lane][0];
#pragma unroll
            for (int reg = 0; reg < 4; ++reg) {
                const int row = b0 + 16 * m + quad * 4 + reg;
                out[(size_t)row * 64 + nt * 16 + m_in] = r[reg];
            }
        }
    }
}

extern "C" void kernel_launch(void* const* d_in, const int* in_sizes, int n_in,
                              void* d_out, int out_size, void* d_ws, size_t ws_size,
                              hipStream_t stream) {
    const float* X    = (const float*)d_in[0];
    const float* tt   = (const float*)d_in[1];
    const float* mean = (const float*)d_in[2];
    const float* std_ = (const float*)d_in[3];
    const float* W    = (const float*)d_in[4];
    float* out = (float*)d_out;

    // workspace: prm (float4 x 4096 = 64 KiB) | Wpk (bf16 x 65*512*8 = 520 KiB)
    float* prm = (float*)d_ws;
    unsigned short* Wpk = (unsigned short*)((char*)d_ws + 65536);

    fq_prep<<<146, 256, 0, stream>>>(tt, mean, std_, W, prm, Wpk);

    const int nblocks = 32768 / BLOCK_B;  // 512 blocks x 512 thr = 4096 waves
    fq_main<<<nblocks, 512, 0, stream>>>(X, (const float4*)prm,
                                         (const bf16x8*)Wpk, out);
}

// Round 7
// 108.016 us; speedup vs baseline: 2.5599x; 2.5599x over previous
//
#include <hip/hip_runtime.h>
#include <hip/hip_bf16.h>

#define F 64
#define R 64
#define O 64
#define BLOCK_B 64   // batch rows per block (512 threads, 8 waves)

typedef short bf16x8 __attribute__((ext_vector_type(8)));
typedef float f32x4 __attribute__((ext_vector_type(4)));
typedef float f32x2 __attribute__((ext_vector_type(2)));

static __device__ __forceinline__ short f2bf(float f) {
    unsigned u = __builtin_bit_cast(unsigned, f);
    unsigned r = (u + 0x7fffu + ((u >> 16) & 1u)) >> 16;
    return (short)r;
}

// ---------------------------------------------------------------------------
// Prep kernel (flat, 146 blocks x 256) — proven variant from rounds 3/6.
//   threads [0, 33280): pack W (fp32) -> Wpk (bf16, MFMA B-fragment order):
//     dst bf16x8 idx = ((nt*65 + f)*2 + kk)*64 + lane
//     elem j = W[o][f*64 + r], o = nt*16+(lane&15), r = (lane>>4)*8 + j + kk*32
//   threads [33280, 37376): prm[u] = {s, mn*s, t, c}, u = f*64 + r
// ---------------------------------------------------------------------------
__global__ __launch_bounds__(256) void fq_prep(
        const float* __restrict__ tt, const float* __restrict__ mean,
        const float* __restrict__ std_, const float* __restrict__ W,
        float* __restrict__ prm, unsigned short* __restrict__ Wpk)
{
    const int tg = blockIdx.x * 256 + threadIdx.x;
    if (tg < 65 * 512) {
        const int f    = tg >> 9;
        const int u8   = tg & 511;
        const int lane = u8 & 63;
        const int kk   = (u8 >> 6) & 1;
        const int nt   = u8 >> 7;
        const int o    = nt * 16 + (lane & 15);
        const int rb   = ((lane >> 4) << 3) + kk * 32;
        const float* src = W + o * 4160 + f * 64 + rb;
        unsigned short v[8];
#pragma unroll
        for (int j = 0; j < 8; ++j) v[j] = (unsigned short)f2bf(src[j]);
        const int dst = ((nt * 65 + f) * 2 + kk) * 64 + lane;
        *(bf16x8*)(Wpk + (size_t)dst * 8) = *(bf16x8*)v;
    } else if (tg < 65 * 512 + 4096) {
        const int u = tg - 65 * 512;
        float sd = std_[u];
        float mn = mean[u];
        float th = tanhf(tt[u]);
        float s  = 1.2011224087864498f / sd;  // sqrt(log2(e)) / std
        float4 p;
        p.x = s;
        p.y = mn * s;
        p.z = th;
        p.w = 0.5f * (1.0f - th);
        ((float4*)prm)[u] = p;
    }
}

// ---------------------------------------------------------------------------
// Main fused kernel: block = 64 batch rows, 512 threads (8 waves).
// wave w: nt = w>>1 (16 output cols), g = w&1 (rows 32g..32g+31, 2 mrow tiles).
// The two waves of each nt issue identical W addresses (in-block L1 sharing).
// X is loaded into registers at the top, written to xt AFTER stage 1
// (overlaps the global fetch with membership math; one barrier).
// Stage 2: distance-2 register prefetch of W fragment pairs.
// ---------------------------------------------------------------------------
__global__ __launch_bounds__(512, 2) void fq_main(
        const float* __restrict__ X,
        const float4* __restrict__ prm,
        const bf16x8* __restrict__ Wp,
        float* __restrict__ out)
{
    __shared__ __align__(16) float xt[64][68];        // [f][row]
    __shared__ __align__(16) float fire_lds[64][68];  // [row][r]
    __shared__ float rinv[BLOCK_B];

    const int t    = threadIdx.x;
    const int lane = t & 63;
    const int w    = __builtin_amdgcn_readfirstlane(t >> 6);  // wave 0..7
    const int b0   = blockIdx.x * BLOCK_B;

    // ---- issue X loads early (held in registers through stage 1) -----------
    const int xrow = t >> 4;          // 0..31
    const int xf4  = (t & 15) * 4;
    float4 xh0 = *(const float4*)(X + (size_t)(b0 + xrow) * 64 + xf4);
    float4 xh1 = *(const float4*)(X + (size_t)(b0 + xrow + 32) * 64 + xf4);

    // ---- stage 1: firing strengths, rows 8w..8w+7, lane = r ----------------
    {
        f32x2 fire2[4];
#pragma unroll
        for (int i = 0; i < 4; ++i) fire2[i] = (f32x2){1.f, 1.f};
        const float* Xw = X + (size_t)(b0 + 8 * w) * 64;
        float4 p = prm[lane];          // f = 0
#pragma unroll 2
        for (int f = 0; f < F; ++f) {
            const int pf = (f + 1 < 64) ? f + 1 : 63;
            float4 pn = prm[pf * 64 + lane];      // distance-1 prefetch
            f32x2 t2 = (f32x2){p.z, p.z};
            f32x2 c2 = (f32x2){p.w, p.w};
#pragma unroll
            for (int i = 0; i < 4; ++i) {
                float x0 = Xw[(2 * i) * 64 + f];      // wave-uniform -> s_load
                float x1 = Xw[(2 * i + 1) * 64 + f];
                f32x2 z;
                z.x = __builtin_fmaf(x0, p.x, -p.y);
                z.y = __builtin_fmaf(x1, p.x, -p.y);
                f32x2 nz = -(z * z);
                f32x2 g;
                g.x = __builtin_amdgcn_exp2f(nz.x);
                g.y = __builtin_amdgcn_exp2f(nz.y);
                fire2[i] *= g * t2 + c2;
            }
            p = pn;
        }
        // write X slab (transposed) and fire rows, then one barrier
        xt[xf4 + 0][xrow] = xh0.x;  xt[xf4 + 0][xrow + 32] = xh1.x;
        xt[xf4 + 1][xrow] = xh0.y;  xt[xf4 + 1][xrow + 32] = xh1.y;
        xt[xf4 + 2][xrow] = xh0.z;  xt[xf4 + 2][xrow + 32] = xh1.z;
        xt[xf4 + 3][xrow] = xh0.w;  xt[xf4 + 3][xrow + 32] = xh1.w;
        const int r0 = 8 * w;
#pragma unroll
        for (int i = 0; i < 4; ++i) {
            fire_lds[r0 + 2 * i][lane]     = fire2[i].x;
            fire_lds[r0 + 2 * i + 1][lane] = fire2[i].y;
        }
    }
    __syncthreads();

    // ---- row sums: 8 threads per row, shuffle-reduce -----------------------
    {
        const int row = t >> 3;
        const int c8  = (t & 7) * 8;
        f32x4 s0 = *(const f32x4*)&fire_lds[row][c8];
        f32x4 s1 = *(const f32x4*)&fire_lds[row][c8 + 4];
        float s = (s0[0] + s0[1]) + (s0[2] + s0[3]) +
                  (s1[0] + s1[1]) + (s1[2] + s1[3]);
        s += __shfl_xor(s, 1);
        s += __shfl_xor(s, 2);
        s += __shfl_xor(s, 4);
        if ((t & 7) == 0) rinv[row] = 1.0f / s;
    }
    __syncthreads();

    // ---- stage 2: 2 row-tiles per wave, one W stream, dist-2 prefetch ------
    const int m_in = lane & 15;
    const int quad = lane >> 4;
    const int nt   = w >> 1;
    const int g    = w & 1;
    const int q8   = quad * 8;

    bf16x8 wfrag[2][2];   // [mm][kk], rows 32g + 16mm + m_in
#pragma unroll
    for (int mm = 0; mm < 2; ++mm) {
        const int myrow = 32 * g + 16 * mm + m_in;
        const float rs  = rinv[myrow];
#pragma unroll
        for (int kk = 0; kk < 2; ++kk) {
            f32x4 a = *(const f32x4*)&fire_lds[myrow][q8 + kk * 32];
            f32x4 b = *(const f32x4*)&fire_lds[myrow][q8 + kk * 32 + 4];
            wfrag[mm][kk][0] = f2bf(a[0] * rs); wfrag[mm][kk][1] = f2bf(a[1] * rs);
            wfrag[mm][kk][2] = f2bf(a[2] * rs); wfrag[mm][kk][3] = f2bf(a[3] * rs);
            wfrag[mm][kk][4] = f2bf(b[0] * rs); wfrag[mm][kk][5] = f2bf(b[1] * rs);
            wfrag[mm][kk][6] = f2bf(b[2] * rs); wfrag[mm][kk][7] = f2bf(b[3] * rs);
        }
    }

    const bf16x8* wpb = Wp + (size_t)(nt * 130) * 64 + lane;

    f32x4 acc[2];
    acc[0] = (f32x4){0.f, 0.f, 0.f, 0.f};
    acc[1] = (f32x4){0.f, 0.f, 0.f, 0.f};
    const f32x4 z4 = (f32x4){0.f, 0.f, 0.f, 0.f};

    // pipeline: two f-slabs in flight (even/odd slots), prefetch f+2
    bf16x8 pe0 = wpb[0 * 64],  pe1 = wpb[1 * 64];     // f = 0
    bf16x8 po0 = wpb[2 * 64],  po1 = wpb[3 * 64];     // f = 1
#pragma unroll 2
    for (int i = 0; i < 32; ++i) {
        const int fe = 2 * i, fo = 2 * i + 1;
        bf16x8 ce0 = pe0, ce1 = pe1, co0 = po0, co1 = po1;
        const int se = (fe + 2 <= 64) ? fe + 2 : 64;   // clamp to bias slab
        const int so = (fo + 2 <= 64) ? fo + 2 : 64;
        pe0 = wpb[(2 * se) * 64];  pe1 = wpb[(2 * se + 1) * 64];
        po0 = wpb[(2 * so) * 64];  po1 = wpb[(2 * so + 1) * 64];
#pragma unroll
        for (int mm = 0; mm < 2; ++mm) {
            f32x4 U = __builtin_amdgcn_mfma_f32_16x16x32_bf16(wfrag[mm][0], ce0, z4, 0, 0, 0);
            U = __builtin_amdgcn_mfma_f32_16x16x32_bf16(wfrag[mm][1], ce1, U, 0, 0, 0);
            f32x4 xv = *(const f32x4*)&xt[fe][32 * g + 16 * mm + quad * 4];
#pragma unroll
            for (int reg = 0; reg < 4; ++reg)
                acc[mm][reg] = __builtin_fmaf(xv[reg], U[reg], acc[mm][reg]);
        }
#pragma unroll
        for (int mm = 0; mm < 2; ++mm) {
            f32x4 U = __builtin_amdgcn_mfma_f32_16x16x32_bf16(wfrag[mm][0], co0, z4, 0, 0, 0);
            U = __builtin_amdgcn_mfma_f32_16x16x32_bf16(wfrag[mm][1], co1, U, 0, 0, 0);
            f32x4 xv = *(const f32x4*)&xt[fo][32 * g + 16 * mm + quad * 4];
#pragma unroll
            for (int reg = 0; reg < 4; ++reg)
                acc[mm][reg] = __builtin_fmaf(xv[reg], U[reg], acc[mm][reg]);
        }
    }

    // bias slab (x = 1): pair already resident in pe0/pe1 (prefetched at i=31)
#pragma unroll
    for (int mm = 0; mm < 2; ++mm) {
        f32x4 U = __builtin_amdgcn_mfma_f32_16x16x32_bf16(wfrag[mm][0], pe0, z4, 0, 0, 0);
        U = __builtin_amdgcn_mfma_f32_16x16x32_bf16(wfrag[mm][1], pe1, U, 0, 0, 0);
#pragma unroll
        for (int reg = 0; reg < 4; ++reg)
            acc[mm][reg] += U[reg];
    }

    // epilogue: C/D layout col = lane&15, row = quad*4 + reg
#pragma unroll
    for (int mm = 0; mm < 2; ++mm)
#pragma unroll
        for (int reg = 0; reg < 4; ++reg) {
            const int row = b0 + 32 * g + 16 * mm + quad * 4 + reg;
            out[(size_t)row * 64 + nt * 16 + m_in] = acc[mm][reg];
        }
}

extern "C" void kernel_launch(void* const* d_in, const int* in_sizes, int n_in,
                              void* d_out, int out_size, void* d_ws, size_t ws_size,
                              hipStream_t stream) {
    const float* X    = (const float*)d_in[0];
    const float* tt   = (const float*)d_in[1];
    const float* mean = (const float*)d_in[2];
    const float* std_ = (const float*)d_in[3];
    const float* W    = (const float*)d_in[4];
    float* out = (float*)d_out;

    // workspace: prm (float4 x 4096 = 64 KiB) | Wpk (bf16 x 65*512*8 = 520 KiB)
    float* prm = (float*)d_ws;
    unsigned short* Wpk = (unsigned short*)((char*)d_ws + 65536);

    fq_prep<<<146, 256, 0, stream>>>(tt, mean, std_, W, prm, Wpk);

    const int nblocks = 32768 / BLOCK_B;  // 512 blocks x 512 thr = 4096 waves
    fq_main<<<nblocks, 512, 0, stream>>>(X, (const float4*)prm,
                                         (const bf16x8*)Wpk, out);
}